// Round 24
// baseline (65.944 us; speedup 1.0000x reference)
//
#include <hip/hip_runtime.h>

#define B_   2048
#define T1_  31
#define D_   128
#define MB_  8

// dynamic-LDS layout (131072 B total)
#define HB_    0        // 4 KB: h double-buffer [2][8 rows][256 B]
#define AXB_   4096     // 64 KB: accx f32 dbuf [2][8 csets][64 lanes][16 f32]
#define WXB_   69632    // 60 KB: wx slots [30][8 rows][256 B] (slot0 recycled)
#define LDS_TOT 131072
#define XWSZ 61440      // fallback kernel's wx region size

typedef __attribute__((ext_vector_type(8))) short bf16x8;
typedef __attribute__((ext_vector_type(4))) float f32x4;
typedef __attribute__((ext_vector_type(2))) float f32x2;

#define L2E  1.4426950408889634f
#define L2E2 2.8853900817779268f

__device__ __forceinline__ unsigned cvt_pk_bf16(float lo, float hi) {
    unsigned r;
    asm("v_cvt_pk_bf16_f32 %0, %1, %2" : "=v"(r) : "v"(lo), "v"(hi));
    return r;
}
__device__ __forceinline__ float rcpf_(float x)  { return __builtin_amdgcn_rcpf(x); }
__device__ __forceinline__ float exp2f_(float x) { return __builtin_amdgcn_exp2f(x); }
__device__ __forceinline__ float sg(float xp)  { return rcpf_(1.0f + exp2f_(-xp)); }
__device__ __forceinline__ float th2(float y)  { return fmaf(-2.0f, rcpf_(1.0f + exp2f_(y)), 1.0f); }

#define BAR_LDS() asm volatile("s_waitcnt lgkmcnt(0)\n\ts_barrier" ::: "memory")

// ==================== primary: 16-wave role-split ============================
// waves 0-7 (h-consumers): hold Whh-half weights; per step: seed acc from LDS
//   accx, 16 h-MFMAs, EW, publish h. waves 8-15 (x-producers): hold Wih-half;
//   per step: read wx frags, 16 bias-seeded x-MFMAs, publish accx(t+1).
// 4 waves/SIMD: producer work fills consumer dependency stalls.
__global__ __launch_bounds__(1024, 4) void enc_split(
    const float* __restrict__ in,  const float* __restrict__ Wih,
    const float* __restrict__ Whh, const float* __restrict__ bih,
    const float* __restrict__ bhh, const float* __restrict__ aw,
    float* __restrict__ outW, float* __restrict__ outE)
{
    extern __shared__ char L[];
    const int tid  = threadIdx.x;
    const int lane = tid & 63;
    const int wv   = tid >> 6;            // 0..15
    const bool isH = (wv < 8);
    const int cset = isH ? wv : (wv - 8); // gate-column set 0..7
    const int b0   = blockIdx.x * MB_;
    const int l15  = lane & 15;
    const int lq   = lane >> 4;
    const int col  = cset * 16 + l15;

    // ---- role-split weights: h-waves Whh (k 128..255), x-waves Wih (k 0..127)
    bf16x8 bw[4][4];
    #pragma unroll
    for (int s = 0; s < 4; ++s) {
        const float scl = (s == 2) ? L2E2 : L2E;
        int n = s * 128 + col;
        const float* wbase = isH ? (Whh + n * D_) : (Wih + n * D_);
        #pragma unroll
        for (int kf = 0; kf < 4; ++kf) {
            const float* wp = wbase + kf * 32 + lq * 8;
            float4 fa = *(const float4*)(wp);
            float4 fb = *(const float4*)(wp + 4);
            union { bf16x8 v; unsigned u[4]; } tmp;
            tmp.u[0] = cvt_pk_bf16(fa.x * scl, fa.y * scl);
            tmp.u[1] = cvt_pk_bf16(fa.z * scl, fa.w * scl);
            tmp.u[2] = cvt_pk_bf16(fb.x * scl, fb.y * scl);
            tmp.u[3] = cvt_pk_bf16(fb.z * scl, fb.w * scl);
            bw[s][kf] = tmp.v;
        }
    }
    float bsv0 = 0.f, bsv1 = 0.f, bsv2 = 0.f, bsv3 = 0.f;
    if (!isH) {      // bias seeds live only on producer waves
        bsv0 = (bih[col]       + bhh[col])       * L2E;
        bsv1 = (bih[128 + col] + bhh[128 + col]) * L2E;
        bsv2 = (bih[256 + col] + bhh[256 + col]) * L2E2;
        bsv3 = (bih[384 + col] + bhh[384 + col]) * L2E;
    }

    // ---- pre-phase (h-waves only): x_score, softmax, outW, wx staging --------
    const int mg = cset;
    const int wxbyte = (4 * lane) ^ (mg << 4);
    unsigned wx30 = 0;
    if (isH) {
        const int d0 = 2 * lane;
        const float* pin = in + (size_t)(b0 + mg) * (T1_ * D_) + d0;
        float2 xc[T1_];
        #pragma unroll
        for (int t = 0; t < T1_; ++t)
            xc[t] = *(const float2*)(pin + t * D_);

        float xs0 = 0.f, xs1 = 0.f;
        #pragma unroll
        for (int t = 0; t < T1_; ++t) {
            float wt = aw[2 * D_ + t];
            xs0 = fmaf(wt, xc[t].x, xs0);
            xs1 = fmaf(wt, xc[t].y, xs1);
        }
        float mx = fmaxf(xs0, xs1);
        #pragma unroll
        for (int o = 32; o > 0; o >>= 1) mx = fmaxf(mx, __shfl_xor(mx, o));
        float e0 = exp2f_((xs0 - mx) * L2E), e1 = exp2f_((xs1 - mx) * L2E);
        float ss = e0 + e1;
        #pragma unroll
        for (int o = 32; o > 0; o >>= 1) ss += __shfl_xor(ss, o);
        float inv = 1.0f / ss;
        const float a0 = e0 * inv, a1 = e1 * inv;

        float* outWp = outW + (size_t)(b0 + mg) * (T1_ * D_) + d0;
        #pragma unroll
        for (int t = 0; t < T1_; ++t) {
            float w0 = a0 * xc[t].x, w1 = a1 * xc[t].y;
            f32x2 wsv; wsv[0] = w0; wsv[1] = w1;
            __builtin_nontemporal_store(wsv, (f32x2*)(outWp + t * D_));
            unsigned u = cvt_pk_bf16(w0, w1);
            if (t < 30) *(unsigned*)(L + WXB_ + t * 2048 + mg * 256 + wxbyte) = u;
            else        wx30 = u;
        }
        ((unsigned*)(L + HB_))[tid]       = 0u;   // tid 0..511 covers 4 KB
        ((unsigned*)(L + HB_))[tid + 512] = 0u;
    }
    BAR_LDS();                                    // staging + h-zero visible

    // ---- fixed per-lane vaddrs -----------------------------------------------
    const int arow = l15 & 7;
    const int asw  = arow << 4;
    const char* wxv[4];  const char* hfv[4];
    #pragma unroll
    for (int kf = 0; kf < 4; ++kf) {
        int fo = arow * 256 + ((kf * 64 + lq * 16) ^ asw);
        wxv[kf] = L + WXB_ + fo;                  // + slot*2048 imm
        hfv[kf] = L + HB_  + fo;                  // + parity*2048 imm
    }
    char* axp = L + AXB_ + cset * 4096 + lane * 64;   // + buf*32768 + s*16 imm

    // ---- producer prologue: accx(0) into buf0 --------------------------------
    if (!isH) {
        bf16x8 f[4];
        #pragma unroll
        for (int kf = 0; kf < 4; ++kf)
            f[kf] = *(const bf16x8*)(wxv[kf]);        // slot 0
        const float bs_[4] = {bsv0, bsv1, bsv2, bsv3};
        #pragma unroll
        for (int s = 0; s < 4; ++s) {
            float b = bs_[s];
            f32x4 a = {b, b, b, b};
            #pragma unroll
            for (int kf = 0; kf < 4; ++kf)
                a = __builtin_amdgcn_mfma_f32_16x16x32_bf16(f[kf], bw[s][kf], a, 0, 0, 0);
            *(f32x4*)(axp + s * 16) = a;              // buf0
        }
    }
    BAR_LDS();                                        // accx(0) visible

    // ---- main loop -----------------------------------------------------------
    const int rb   = ((lane & 31) >> 4) * 4 + ((lane >> 5) << 1);
    const bool hi32 = (lane >= 32);
    const int wb0 = rb * 256       + ((2 * col) ^ (rb << 4));
    const int wb1 = (rb + 1) * 256 + ((2 * col) ^ ((rb + 1) << 4));
    float* outE0 = outE + (size_t)(b0 + rb)     * (T1_ * D_) + col;
    float* outE1 = outE + (size_t)(b0 + rb + 1) * (T1_ * D_) + col;
    float cs0 = 0.f, cs1 = 0.f;

    #pragma unroll
    for (int t = 0; t < T1_; ++t) {
        if (isH) {
            // seed = accx(t) from LDS; then h-MFMA chain
            f32x4 acc[4];
            #pragma unroll
            for (int s = 0; s < 4; ++s)
                acc[s] = *(const f32x4*)(axp + (t & 1) * 32768 + s * 16);
            bf16x8 hfr[4];
            #pragma unroll
            for (int kf = 0; kf < 4; ++kf)
                hfr[kf] = *(const bf16x8*)(hfv[kf] + (t & 1) * 2048);
            #pragma unroll
            for (int s = 0; s < 4; ++s) {
                #pragma unroll
                for (int kf = 0; kf < 4; ++kf)
                    acc[s] = __builtin_amdgcn_mfma_f32_16x16x32_bf16(hfr[kf], bw[s][kf], acc[s], 0, 0, 0);
            }
            if (t == 1)   // recycle slot0 with wx[30]; consumed at window 29
                *(unsigned*)(L + WXB_ + mg * 256 + wxbyte) = wx30;

            float gq0[4], gq1[4];
            #pragma unroll
            for (int s = 0; s < 4; ++s) {
                gq0[s] = hi32 ? acc[s][2] : acc[s][0];
                gq1[s] = hi32 ? acc[s][3] : acc[s][1];
            }
            float si0 = sg(gq0[0]), si1 = sg(gq1[0]);
            float sf0 = sg(gq0[1]), sf1 = sg(gq1[1]);
            float tg0 = th2(gq0[2]), tg1 = th2(gq1[2]);
            float so0 = sg(gq0[3]), so1 = sg(gq1[3]);
            float cn0 = fmaf(sf0, cs0, si0 * tg0);  cs0 = cn0;
            float cn1 = fmaf(sf1, cs1, si1 * tg1);  cs1 = cn1;
            float hh0 = so0 * th2(cn0 * L2E2);
            float hh1 = so1 * th2(cn1 * L2E2);
            unsigned hu = cvt_pk_bf16(hh0, hh1);

            if (t < 30) {
                char* hw = L + HB_ + (((t + 1) & 1) * 2048);
                *(unsigned short*)(hw + wb0) = (unsigned short)(hu & 0xffffu);
                *(unsigned short*)(hw + wb1) = (unsigned short)(hu >> 16);
            }
            __builtin_nontemporal_store(hh0, outE0 + t * D_);
            __builtin_nontemporal_store(hh1, outE1 + t * D_);
        } else {
            if (t < 30) {     // produce accx(t+1) into buf (t+1)&1
                const int slot = (t + 1 == 30) ? 0 : (t + 1);
                bf16x8 f[4];
                #pragma unroll
                for (int kf = 0; kf < 4; ++kf)
                    f[kf] = *(const bf16x8*)(wxv[kf] + slot * 2048);
                const float bs_[4] = {bsv0, bsv1, bsv2, bsv3};
                #pragma unroll
                for (int s = 0; s < 4; ++s) {
                    float b = bs_[s];
                    f32x4 a = {b, b, b, b};
                    #pragma unroll
                    for (int kf = 0; kf < 4; ++kf)
                        a = __builtin_amdgcn_mfma_f32_16x16x32_bf16(f[kf], bw[s][kf], a, 0, 0, 0);
                    *(f32x4*)(axp + ((t + 1) & 1) * 32768 + s * 16) = a;
                }
            }
        }
        BAR_LDS();
    }
}

// ==================== fallback: proven R23 kernel ============================
__global__ __launch_bounds__(512, 2) void enc_fused(
    const float* __restrict__ in,  const float* __restrict__ Wih,
    const float* __restrict__ Whh, const float* __restrict__ bih,
    const float* __restrict__ bhh, const float* __restrict__ aw,
    float* __restrict__ outW, float* __restrict__ outE)
{
    const int tid  = threadIdx.x;
    const int lane = tid & 63;
    const int wv   = tid >> 6;
    const int b0   = blockIdx.x * MB_;
    const int l15  = lane & 15;
    const int lq   = lane >> 4;

    __shared__ __align__(16) char L[XWSZ + 4096];

    const int mg = wv;
    const int d0 = 2 * lane;
    const float* pin = in + (size_t)(b0 + mg) * (T1_ * D_) + d0;
    float2 xc[T1_];
    #pragma unroll
    for (int t = 0; t < T1_; ++t)
        xc[t] = *(const float2*)(pin + t * D_);

    bf16x8 bw[4][8];
    #pragma unroll
    for (int s = 0; s < 4; ++s) {
        const float scl = (s == 2) ? L2E2 : L2E;
        int n = s * 128 + wv * 16 + l15;
        #pragma unroll
        for (int kf = 0; kf < 8; ++kf) {
            int kb = kf * 32 + lq * 8;
            const float* wp = (kf < 4) ? (Wih + n * D_ + kb) : (Whh + n * D_ + (kb - 128));
            float4 fa = *(const float4*)(wp);
            float4 fb = *(const float4*)(wp + 4);
            union { bf16x8 v; unsigned u[4]; } tmp;
            tmp.u[0] = cvt_pk_bf16(fa.x * scl, fa.y * scl);
            tmp.u[1] = cvt_pk_bf16(fa.z * scl, fa.w * scl);
            tmp.u[2] = cvt_pk_bf16(fb.x * scl, fb.y * scl);
            tmp.u[3] = cvt_pk_bf16(fb.z * scl, fb.w * scl);
            bw[s][kf] = tmp.v;
        }
    }
    const int col = wv * 16 + l15;
    const float bsv[4] = { (bih[col]       + bhh[col])       * L2E,
                           (bih[128 + col] + bhh[128 + col]) * L2E,
                           (bih[256 + col] + bhh[256 + col]) * L2E2,
                           (bih[384 + col] + bhh[384 + col]) * L2E };

    float xs0 = 0.f, xs1 = 0.f;
    #pragma unroll
    for (int t = 0; t < T1_; ++t) {
        float wt = aw[2 * D_ + t];
        xs0 = fmaf(wt, xc[t].x, xs0);
        xs1 = fmaf(wt, xc[t].y, xs1);
    }
    float mx = fmaxf(xs0, xs1);
    #pragma unroll
    for (int o = 32; o > 0; o >>= 1) mx = fmaxf(mx, __shfl_xor(mx, o));
    float e0 = exp2f_((xs0 - mx) * L2E), e1 = exp2f_((xs1 - mx) * L2E);
    float ss = e0 + e1;
    #pragma unroll
    for (int o = 32; o > 0; o >>= 1) ss += __shfl_xor(ss, o);
    float inv = 1.0f / ss;
    const float a0 = e0 * inv, a1 = e1 * inv;

    const int wxbyte = (4 * lane) ^ (mg << 4);
    float* outWp = outW + (size_t)(b0 + mg) * (T1_ * D_) + d0;
    unsigned wx30 = 0;
    #pragma unroll
    for (int t = 0; t < T1_; ++t) {
        float w0 = a0 * xc[t].x, w1 = a1 * xc[t].y;
        f32x2 wsv; wsv[0] = w0; wsv[1] = w1;
        __builtin_nontemporal_store(wsv, (f32x2*)(outWp + t * D_));
        unsigned u = cvt_pk_bf16(w0, w1);
        if (t < 30) *(unsigned*)(L + t * 2048 + mg * 256 + wxbyte) = u;
        else        wx30 = u;
    }
    ((unsigned*)(L + XWSZ))[tid]       = 0u;
    ((unsigned*)(L + XWSZ))[tid + 512] = 0u;
    BAR_LDS();

    const int arow = l15 & 7;
    const int asw  = arow << 4;
    const char* vb[4];
    #pragma unroll
    for (int kf = 0; kf < 4; ++kf)
        vb[kf] = L + arow * 256 + ((kf * 64 + lq * 16) ^ asw);

    const int rb   = ((lane & 31) >> 4) * 4 + ((lane >> 5) << 1);
    const bool hi32 = (lane >= 32);
    const int wb0 = rb * 256       + ((2 * col) ^ (rb << 4));
    const int wb1 = (rb + 1) * 256 + ((2 * col) ^ ((rb + 1) << 4));
    float* outE0 = outE + (size_t)(b0 + rb)     * (T1_ * D_) + col;
    float* outE1 = outE + (size_t)(b0 + rb + 1) * (T1_ * D_) + col;

    float cs0 = 0.f, cs1 = 0.f;
    f32x4 accx[4];
    bf16x8 wxn[4];
    {
        bf16x8 w0[4];
        #pragma unroll
        for (int kf = 0; kf < 4; ++kf)
            w0[kf] = *(const bf16x8*)(vb[kf]);
        #pragma unroll
        for (int s = 0; s < 4; ++s) {
            float b = bsv[s];
            f32x4 aA = {b, b, b, b};
            #pragma unroll
            for (int kf = 0; kf < 4; ++kf)
                aA = __builtin_amdgcn_mfma_f32_16x16x32_bf16(w0[kf], bw[s][kf], aA, 0, 0, 0);
            accx[s] = aA;
        }
        #pragma unroll
        for (int kf = 0; kf < 4; ++kf)
            wxn[kf] = *(const bf16x8*)(vb[kf] + 2048);
    }

    #pragma unroll
    for (int t = 0; t < T1_; ++t) {
        bf16x8 hfr[4];
        #pragma unroll
        for (int kf = 0; kf < 4; ++kf)
            hfr[kf] = *(const bf16x8*)(vb[kf] + XWSZ + (t & 1) * 2048);

        f32x4 acc[4];
        #pragma unroll
        for (int s = 0; s < 4; ++s) {
            f32x4 a_ = accx[s];
            #pragma unroll
            for (int kf = 0; kf < 4; ++kf)
                a_ = __builtin_amdgcn_mfma_f32_16x16x32_bf16(hfr[kf], bw[s][4 + kf], a_, 0, 0, 0);
            acc[s] = a_;
        }

        bf16x8 wxn2[4];
        if (t < 29) {
            const int slot = (t + 2 == 30) ? 0 : (t + 2);
            #pragma unroll
            for (int kf = 0; kf < 4; ++kf)
                wxn2[kf] = *(const bf16x8*)(vb[kf] + slot * 2048);
        }
        if (t == 1)
            *(unsigned*)(L + mg * 256 + wxbyte) = wx30;

        if (t < 30) {
            #pragma unroll
            for (int s = 0; s < 4; ++s) {
                float b = bsv[s];
                f32x4 aA = {b, b, b, b};
                #pragma unroll
                for (int kf = 0; kf < 4; ++kf)
                    aA = __builtin_amdgcn_mfma_f32_16x16x32_bf16(wxn[kf], bw[s][kf], aA, 0, 0, 0);
                accx[s] = aA;
            }
        }

        float gq0[4], gq1[4];
        #pragma unroll
        for (int s = 0; s < 4; ++s) {
            gq0[s] = hi32 ? acc[s][2] : acc[s][0];
            gq1[s] = hi32 ? acc[s][3] : acc[s][1];
        }

        float si0 = sg(gq0[0]), si1 = sg(gq1[0]);
        float sf0 = sg(gq0[1]), sf1 = sg(gq1[1]);
        float tg0 = th2(gq0[2]), tg1 = th2(gq1[2]);
        float so0 = sg(gq0[3]), so1 = sg(gq1[3]);
        float cn0 = fmaf(sf0, cs0, si0 * tg0);  cs0 = cn0;
        float cn1 = fmaf(sf1, cs1, si1 * tg1);  cs1 = cn1;
        float hh0 = so0 * th2(cn0 * L2E2);
        float hh1 = so1 * th2(cn1 * L2E2);
        unsigned hu = cvt_pk_bf16(hh0, hh1);

        if (t < 30) {
            char* hw = L + XWSZ + (((t + 1) & 1) * 2048);
            *(unsigned short*)(hw + wb0) = (unsigned short)(hu & 0xffffu);
            *(unsigned short*)(hw + wb1) = (unsigned short)(hu >> 16);
        }
        __builtin_nontemporal_store(hh0, outE0 + t * D_);
        __builtin_nontemporal_store(hh1, outE1 + t * D_);

        if (t < 29) {
            #pragma unroll
            for (int kf = 0; kf < 4; ++kf) wxn[kf] = wxn2[kf];
        }

        BAR_LDS();
    }
}

extern "C" void kernel_launch(void* const* d_in, const int* in_sizes, int n_in,
                              void* d_out, int out_size, void* d_ws, size_t ws_size,
                              hipStream_t stream) {
    const float* in  = (const float*)d_in[0];
    const float* Wih = (const float*)d_in[1];
    const float* Whh = (const float*)d_in[2];
    const float* bih = (const float*)d_in[3];
    const float* bhh = (const float*)d_in[4];
    const float* aw  = (const float*)d_in[5];
    // d_in[6] (attn_b) is mathematically dead: softmax is shift-invariant.

    float* outW = (float*)d_out;
    float* outE = outW + (size_t)B_ * T1_ * D_;

    // 128 KB dynamic LDS needs the opt-in attribute; deterministic fallback to
    // the proven 8-wave kernel if the runtime refuses (same result either way).
    hipError_t e = hipFuncSetAttribute((const void*)enc_split,
                                       hipFuncAttributeMaxDynamicSharedMemorySize,
                                       LDS_TOT);
    if (e == hipSuccess) {
        enc_split<<<dim3(B_ / MB_), dim3(1024), LDS_TOT, stream>>>(
            in, Wih, Whh, bih, bhh, aw, outW, outE);
    } else {
        enc_fused<<<dim3(B_ / MB_), dim3(512), 0, stream>>>(
            in, Wih, Whh, bih, bhh, aw, outW, outE);
    }
}

// Round 25
// 58.018 us; speedup vs baseline: 1.1366x; 1.1366x over previous
//
#include <hip/hip_runtime.h>

#define B_   2048
#define T1_  31
#define D_   128
#define MB_  8

// dynamic-LDS layout (131072 B total)
#define HB_    0        // 4 KB: h double-buffer [2][8 rows][256 B]
#define AXB_   4096     // 64 KB: accx f32 dbuf [2 buf][8 cset][4 s][64 lane][16 B]
#define WXB_   69632    // 60 KB: wx slots [30][8 rows][256 B] (slot0 recycled)
#define LDS_TOT 131072
#define XWSZ 61440      // fallback kernel's wx region size

typedef __attribute__((ext_vector_type(8))) short bf16x8;
typedef __attribute__((ext_vector_type(4))) float f32x4;
typedef __attribute__((ext_vector_type(2))) float f32x2;

#define L2E  1.4426950408889634f
#define L2E2 2.8853900817779268f

__device__ __forceinline__ unsigned cvt_pk_bf16(float lo, float hi) {
    unsigned r;
    asm("v_cvt_pk_bf16_f32 %0, %1, %2" : "=v"(r) : "v"(lo), "v"(hi));
    return r;
}
__device__ __forceinline__ float rcpf_(float x)  { return __builtin_amdgcn_rcpf(x); }
__device__ __forceinline__ float exp2f_(float x) { return __builtin_amdgcn_exp2f(x); }
__device__ __forceinline__ float sg(float xp)  { return rcpf_(1.0f + exp2f_(-xp)); }
__device__ __forceinline__ float th2(float y)  { return fmaf(-2.0f, rcpf_(1.0f + exp2f_(y)), 1.0f); }

#define BAR_LDS() asm volatile("s_waitcnt lgkmcnt(0)\n\ts_barrier" ::: "memory")

// ==================== primary: 16-wave role-split (conflict-free exchange) ===
// waves 0-7 (h-consumers): Whh weights; zero-seeded h-MFMA chain, accx added
//   AFTER the chain (exchange-read latency hides under MFMAs), EW, publish h.
// waves 8-15 (x-producers): Wih weights; bias-seeded accx(t+1) -> LDS.
// Exchange layout [buf][cset][s][lane]: 64 lanes x 16 B contiguous per (s) =
// canonical conflict-free b128 pattern both directions.
__global__ __launch_bounds__(1024, 4) void enc_split(
    const float* __restrict__ in,  const float* __restrict__ Wih,
    const float* __restrict__ Whh, const float* __restrict__ bih,
    const float* __restrict__ bhh, const float* __restrict__ aw,
    float* __restrict__ outW, float* __restrict__ outE)
{
    extern __shared__ char L[];
    const int tid  = threadIdx.x;
    const int lane = tid & 63;
    const int wv   = tid >> 6;            // 0..15
    const bool isH = (wv < 8);
    const int cset = isH ? wv : (wv - 8); // gate-column set 0..7
    const int b0   = blockIdx.x * MB_;
    const int l15  = lane & 15;
    const int lq   = lane >> 4;
    const int col  = cset * 16 + l15;

    // ---- role-split weights: h-waves Whh (k 128..255), x-waves Wih (k 0..127)
    bf16x8 bw[4][4];
    #pragma unroll
    for (int s = 0; s < 4; ++s) {
        const float scl = (s == 2) ? L2E2 : L2E;
        int n = s * 128 + col;
        const float* wbase = isH ? (Whh + n * D_) : (Wih + n * D_);
        #pragma unroll
        for (int kf = 0; kf < 4; ++kf) {
            const float* wp = wbase + kf * 32 + lq * 8;
            float4 fa = *(const float4*)(wp);
            float4 fb = *(const float4*)(wp + 4);
            union { bf16x8 v; unsigned u[4]; } tmp;
            tmp.u[0] = cvt_pk_bf16(fa.x * scl, fa.y * scl);
            tmp.u[1] = cvt_pk_bf16(fa.z * scl, fa.w * scl);
            tmp.u[2] = cvt_pk_bf16(fb.x * scl, fb.y * scl);
            tmp.u[3] = cvt_pk_bf16(fb.z * scl, fb.w * scl);
            bw[s][kf] = tmp.v;
        }
    }
    float bsv0 = 0.f, bsv1 = 0.f, bsv2 = 0.f, bsv3 = 0.f;
    if (!isH) {      // bias seeds live only on producer waves
        bsv0 = (bih[col]       + bhh[col])       * L2E;
        bsv1 = (bih[128 + col] + bhh[128 + col]) * L2E;
        bsv2 = (bih[256 + col] + bhh[256 + col]) * L2E2;
        bsv3 = (bih[384 + col] + bhh[384 + col]) * L2E;
    }

    // ---- pre-phase (h-waves only): x_score, softmax, outW, wx staging --------
    const int mg = cset;
    const int wxbyte = (4 * lane) ^ (mg << 4);
    unsigned wx30 = 0;
    if (isH) {
        const int d0 = 2 * lane;
        const float* pin = in + (size_t)(b0 + mg) * (T1_ * D_) + d0;
        float2 xc[T1_];
        #pragma unroll
        for (int t = 0; t < T1_; ++t)
            xc[t] = *(const float2*)(pin + t * D_);

        float xs0 = 0.f, xs1 = 0.f;
        #pragma unroll
        for (int t = 0; t < T1_; ++t) {
            float wt = aw[2 * D_ + t];
            xs0 = fmaf(wt, xc[t].x, xs0);
            xs1 = fmaf(wt, xc[t].y, xs1);
        }
        float mx = fmaxf(xs0, xs1);
        #pragma unroll
        for (int o = 32; o > 0; o >>= 1) mx = fmaxf(mx, __shfl_xor(mx, o));
        float e0 = exp2f_((xs0 - mx) * L2E), e1 = exp2f_((xs1 - mx) * L2E);
        float ss = e0 + e1;
        #pragma unroll
        for (int o = 32; o > 0; o >>= 1) ss += __shfl_xor(ss, o);
        float inv = 1.0f / ss;
        const float a0 = e0 * inv, a1 = e1 * inv;

        float* outWp = outW + (size_t)(b0 + mg) * (T1_ * D_) + d0;
        #pragma unroll
        for (int t = 0; t < T1_; ++t) {
            float w0 = a0 * xc[t].x, w1 = a1 * xc[t].y;
            f32x2 wsv; wsv[0] = w0; wsv[1] = w1;
            __builtin_nontemporal_store(wsv, (f32x2*)(outWp + t * D_));
            unsigned u = cvt_pk_bf16(w0, w1);
            if (t < 30) *(unsigned*)(L + WXB_ + t * 2048 + mg * 256 + wxbyte) = u;
            else        wx30 = u;
        }
        ((unsigned*)(L + HB_))[tid]       = 0u;   // tid 0..511 covers 4 KB
        ((unsigned*)(L + HB_))[tid + 512] = 0u;
    }
    BAR_LDS();                                    // staging + h-zero visible

    // ---- fixed per-lane vaddrs -----------------------------------------------
    const int arow = l15 & 7;
    const int asw  = arow << 4;
    const char* wxv[4];  const char* hfv[4];
    #pragma unroll
    for (int kf = 0; kf < 4; ++kf) {
        int fo = arow * 256 + ((kf * 64 + lq * 16) ^ asw);
        wxv[kf] = L + WXB_ + fo;                  // + slot*2048 imm
        hfv[kf] = L + HB_  + fo;                  // + parity*2048 imm
    }
    // conflict-free exchange: [buf 32768][cset 4096][s 1024][lane 16]
    char* axp = L + AXB_ + cset * 4096 + lane * 16;   // + buf*32768 + s*1024 imm

    // ---- producer prologue: accx(0) into buf0 --------------------------------
    if (!isH) {
        bf16x8 f[4];
        #pragma unroll
        for (int kf = 0; kf < 4; ++kf)
            f[kf] = *(const bf16x8*)(wxv[kf]);        // slot 0
        const float bs_[4] = {bsv0, bsv1, bsv2, bsv3};
        #pragma unroll
        for (int s = 0; s < 4; ++s) {
            float b = bs_[s];
            f32x4 a = {b, b, b, b};
            #pragma unroll
            for (int kf = 0; kf < 4; ++kf)
                a = __builtin_amdgcn_mfma_f32_16x16x32_bf16(f[kf], bw[s][kf], a, 0, 0, 0);
            *(f32x4*)(axp + s * 1024) = a;            // buf0
        }
    }
    BAR_LDS();                                        // accx(0) visible

    // ---- main loop -----------------------------------------------------------
    const int rb   = ((lane & 31) >> 4) * 4 + ((lane >> 5) << 1);
    const bool hi32 = (lane >= 32);
    const int wb0 = rb * 256       + ((2 * col) ^ (rb << 4));
    const int wb1 = (rb + 1) * 256 + ((2 * col) ^ ((rb + 1) << 4));
    float* outE0 = outE + (size_t)(b0 + rb)     * (T1_ * D_) + col;
    float* outE1 = outE + (size_t)(b0 + rb + 1) * (T1_ * D_) + col;
    float cs0 = 0.f, cs1 = 0.f;

    #pragma unroll
    for (int t = 0; t < T1_; ++t) {
        if (isH) {
            // issue h reads first, then accx reads; MFMAs wait only on hfr,
            // accx lands during the chain and is added after.
            bf16x8 hfr[4];
            #pragma unroll
            for (int kf = 0; kf < 4; ++kf)
                hfr[kf] = *(const bf16x8*)(hfv[kf] + (t & 1) * 2048);
            f32x4 axl[4];
            #pragma unroll
            for (int s = 0; s < 4; ++s)
                axl[s] = *(const f32x4*)(axp + (t & 1) * 32768 + s * 1024);

            f32x4 z[4];
            #pragma unroll
            for (int s = 0; s < 4; ++s) {
                f32x4 a = {0.f, 0.f, 0.f, 0.f};
                #pragma unroll
                for (int kf = 0; kf < 4; ++kf)
                    a = __builtin_amdgcn_mfma_f32_16x16x32_bf16(hfr[kf], bw[s][kf], a, 0, 0, 0);
                z[s] = a;
            }
            if (t == 1)   // recycle slot0 with wx[30]; consumed at window 29
                *(unsigned*)(L + WXB_ + mg * 256 + wxbyte) = wx30;

            float gq0[4], gq1[4];
            #pragma unroll
            for (int s = 0; s < 4; ++s) {
                f32x4 acc = axl[s] + z[s];
                gq0[s] = hi32 ? acc[2] : acc[0];
                gq1[s] = hi32 ? acc[3] : acc[1];
            }
            float si0 = sg(gq0[0]), si1 = sg(gq1[0]);
            float sf0 = sg(gq0[1]), sf1 = sg(gq1[1]);
            float tg0 = th2(gq0[2]), tg1 = th2(gq1[2]);
            float so0 = sg(gq0[3]), so1 = sg(gq1[3]);
            float cn0 = fmaf(sf0, cs0, si0 * tg0);  cs0 = cn0;
            float cn1 = fmaf(sf1, cs1, si1 * tg1);  cs1 = cn1;
            float hh0 = so0 * th2(cn0 * L2E2);
            float hh1 = so1 * th2(cn1 * L2E2);
            unsigned hu = cvt_pk_bf16(hh0, hh1);

            if (t < 30) {
                char* hw = L + HB_ + (((t + 1) & 1) * 2048);
                *(unsigned short*)(hw + wb0) = (unsigned short)(hu & 0xffffu);
                *(unsigned short*)(hw + wb1) = (unsigned short)(hu >> 16);
            }
            __builtin_nontemporal_store(hh0, outE0 + t * D_);
            __builtin_nontemporal_store(hh1, outE1 + t * D_);
        } else {
            if (t < 30) {     // produce accx(t+1) into buf (t+1)&1
                const int slot = (t + 1 == 30) ? 0 : (t + 1);
                bf16x8 f[4];
                #pragma unroll
                for (int kf = 0; kf < 4; ++kf)
                    f[kf] = *(const bf16x8*)(wxv[kf] + slot * 2048);
                const float bs_[4] = {bsv0, bsv1, bsv2, bsv3};
                #pragma unroll
                for (int s = 0; s < 4; ++s) {
                    float b = bs_[s];
                    f32x4 a = {b, b, b, b};
                    #pragma unroll
                    for (int kf = 0; kf < 4; ++kf)
                        a = __builtin_amdgcn_mfma_f32_16x16x32_bf16(f[kf], bw[s][kf], a, 0, 0, 0);
                    *(f32x4*)(axp + ((t + 1) & 1) * 32768 + s * 1024) = a;
                }
            }
        }
        BAR_LDS();
    }
}

// ==================== fallback: proven R23 kernel ============================
__global__ __launch_bounds__(512, 2) void enc_fused(
    const float* __restrict__ in,  const float* __restrict__ Wih,
    const float* __restrict__ Whh, const float* __restrict__ bih,
    const float* __restrict__ bhh, const float* __restrict__ aw,
    float* __restrict__ outW, float* __restrict__ outE)
{
    const int tid  = threadIdx.x;
    const int lane = tid & 63;
    const int wv   = tid >> 6;
    const int b0   = blockIdx.x * MB_;
    const int l15  = lane & 15;
    const int lq   = lane >> 4;

    __shared__ __align__(16) char L[XWSZ + 4096];

    const int mg = wv;
    const int d0 = 2 * lane;
    const float* pin = in + (size_t)(b0 + mg) * (T1_ * D_) + d0;
    float2 xc[T1_];
    #pragma unroll
    for (int t = 0; t < T1_; ++t)
        xc[t] = *(const float2*)(pin + t * D_);

    bf16x8 bw[4][8];
    #pragma unroll
    for (int s = 0; s < 4; ++s) {
        const float scl = (s == 2) ? L2E2 : L2E;
        int n = s * 128 + wv * 16 + l15;
        #pragma unroll
        for (int kf = 0; kf < 8; ++kf) {
            int kb = kf * 32 + lq * 8;
            const float* wp = (kf < 4) ? (Wih + n * D_ + kb) : (Whh + n * D_ + (kb - 128));
            float4 fa = *(const float4*)(wp);
            float4 fb = *(const float4*)(wp + 4);
            union { bf16x8 v; unsigned u[4]; } tmp;
            tmp.u[0] = cvt_pk_bf16(fa.x * scl, fa.y * scl);
            tmp.u[1] = cvt_pk_bf16(fa.z * scl, fa.w * scl);
            tmp.u[2] = cvt_pk_bf16(fb.x * scl, fb.y * scl);
            tmp.u[3] = cvt_pk_bf16(fb.z * scl, fb.w * scl);
            bw[s][kf] = tmp.v;
        }
    }
    const int col = wv * 16 + l15;
    const float bsv[4] = { (bih[col]       + bhh[col])       * L2E,
                           (bih[128 + col] + bhh[128 + col]) * L2E,
                           (bih[256 + col] + bhh[256 + col]) * L2E2,
                           (bih[384 + col] + bhh[384 + col]) * L2E };

    float xs0 = 0.f, xs1 = 0.f;
    #pragma unroll
    for (int t = 0; t < T1_; ++t) {
        float wt = aw[2 * D_ + t];
        xs0 = fmaf(wt, xc[t].x, xs0);
        xs1 = fmaf(wt, xc[t].y, xs1);
    }
    float mx = fmaxf(xs0, xs1);
    #pragma unroll
    for (int o = 32; o > 0; o >>= 1) mx = fmaxf(mx, __shfl_xor(mx, o));
    float e0 = exp2f_((xs0 - mx) * L2E), e1 = exp2f_((xs1 - mx) * L2E);
    float ss = e0 + e1;
    #pragma unroll
    for (int o = 32; o > 0; o >>= 1) ss += __shfl_xor(ss, o);
    float inv = 1.0f / ss;
    const float a0 = e0 * inv, a1 = e1 * inv;

    const int wxbyte = (4 * lane) ^ (mg << 4);
    float* outWp = outW + (size_t)(b0 + mg) * (T1_ * D_) + d0;
    unsigned wx30 = 0;
    #pragma unroll
    for (int t = 0; t < T1_; ++t) {
        float w0 = a0 * xc[t].x, w1 = a1 * xc[t].y;
        f32x2 wsv; wsv[0] = w0; wsv[1] = w1;
        __builtin_nontemporal_store(wsv, (f32x2*)(outWp + t * D_));
        unsigned u = cvt_pk_bf16(w0, w1);
        if (t < 30) *(unsigned*)(L + t * 2048 + mg * 256 + wxbyte) = u;
        else        wx30 = u;
    }
    ((unsigned*)(L + XWSZ))[tid]       = 0u;
    ((unsigned*)(L + XWSZ))[tid + 512] = 0u;
    BAR_LDS();

    const int arow = l15 & 7;
    const int asw  = arow << 4;
    const char* vb[4];
    #pragma unroll
    for (int kf = 0; kf < 4; ++kf)
        vb[kf] = L + arow * 256 + ((kf * 64 + lq * 16) ^ asw);

    const int rb   = ((lane & 31) >> 4) * 4 + ((lane >> 5) << 1);
    const bool hi32 = (lane >= 32);
    const int wb0 = rb * 256       + ((2 * col) ^ (rb << 4));
    const int wb1 = (rb + 1) * 256 + ((2 * col) ^ ((rb + 1) << 4));
    float* outE0 = outE + (size_t)(b0 + rb)     * (T1_ * D_) + col;
    float* outE1 = outE + (size_t)(b0 + rb + 1) * (T1_ * D_) + col;

    float cs0 = 0.f, cs1 = 0.f;
    f32x4 accx[4];
    bf16x8 wxn[4];
    {
        bf16x8 w0[4];
        #pragma unroll
        for (int kf = 0; kf < 4; ++kf)
            w0[kf] = *(const bf16x8*)(vb[kf]);
        #pragma unroll
        for (int s = 0; s < 4; ++s) {
            float b = bsv[s];
            f32x4 aA = {b, b, b, b};
            #pragma unroll
            for (int kf = 0; kf < 4; ++kf)
                aA = __builtin_amdgcn_mfma_f32_16x16x32_bf16(w0[kf], bw[s][kf], aA, 0, 0, 0);
            accx[s] = aA;
        }
        #pragma unroll
        for (int kf = 0; kf < 4; ++kf)
            wxn[kf] = *(const bf16x8*)(vb[kf] + 2048);
    }

    #pragma unroll
    for (int t = 0; t < T1_; ++t) {
        bf16x8 hfr[4];
        #pragma unroll
        for (int kf = 0; kf < 4; ++kf)
            hfr[kf] = *(const bf16x8*)(vb[kf] + XWSZ + (t & 1) * 2048);

        f32x4 acc[4];
        #pragma unroll
        for (int s = 0; s < 4; ++s) {
            f32x4 a_ = accx[s];
            #pragma unroll
            for (int kf = 0; kf < 4; ++kf)
                a_ = __builtin_amdgcn_mfma_f32_16x16x32_bf16(hfr[kf], bw[s][4 + kf], a_, 0, 0, 0);
            acc[s] = a_;
        }

        bf16x8 wxn2[4];
        if (t < 29) {
            const int slot = (t + 2 == 30) ? 0 : (t + 2);
            #pragma unroll
            for (int kf = 0; kf < 4; ++kf)
                wxn2[kf] = *(const bf16x8*)(vb[kf] + slot * 2048);
        }
        if (t == 1)
            *(unsigned*)(L + mg * 256 + wxbyte) = wx30;

        if (t < 30) {
            #pragma unroll
            for (int s = 0; s < 4; ++s) {
                float b = bsv[s];
                f32x4 aA = {b, b, b, b};
                #pragma unroll
                for (int kf = 0; kf < 4; ++kf)
                    aA = __builtin_amdgcn_mfma_f32_16x16x32_bf16(wxn[kf], bw[s][kf], aA, 0, 0, 0);
                accx[s] = aA;
            }
        }

        float gq0[4], gq1[4];
        #pragma unroll
        for (int s = 0; s < 4; ++s) {
            gq0[s] = hi32 ? acc[s][2] : acc[s][0];
            gq1[s] = hi32 ? acc[s][3] : acc[s][1];
        }

        float si0 = sg(gq0[0]), si1 = sg(gq1[0]);
        float sf0 = sg(gq0[1]), sf1 = sg(gq1[1]);
        float tg0 = th2(gq0[2]), tg1 = th2(gq1[2]);
        float so0 = sg(gq0[3]), so1 = sg(gq1[3]);
        float cn0 = fmaf(sf0, cs0, si0 * tg0);  cs0 = cn0;
        float cn1 = fmaf(sf1, cs1, si1 * tg1);  cs1 = cn1;
        float hh0 = so0 * th2(cn0 * L2E2);
        float hh1 = so1 * th2(cn1 * L2E2);
        unsigned hu = cvt_pk_bf16(hh0, hh1);

        if (t < 30) {
            char* hw = L + XWSZ + (((t + 1) & 1) * 2048);
            *(unsigned short*)(hw + wb0) = (unsigned short)(hu & 0xffffu);
            *(unsigned short*)(hw + wb1) = (unsigned short)(hu >> 16);
        }
        __builtin_nontemporal_store(hh0, outE0 + t * D_);
        __builtin_nontemporal_store(hh1, outE1 + t * D_);

        if (t < 29) {
            #pragma unroll
            for (int kf = 0; kf < 4; ++kf) wxn[kf] = wxn2[kf];
        }

        BAR_LDS();
    }
}

extern "C" void kernel_launch(void* const* d_in, const int* in_sizes, int n_in,
                              void* d_out, int out_size, void* d_ws, size_t ws_size,
                              hipStream_t stream) {
    const float* in  = (const float*)d_in[0];
    const float* Wih = (const float*)d_in[1];
    const float* Whh = (const float*)d_in[2];
    const float* bih = (const float*)d_in[3];
    const float* bhh = (const float*)d_in[4];
    const float* aw  = (const float*)d_in[5];
    // d_in[6] (attn_b) is mathematically dead: softmax is shift-invariant.

    float* outW = (float*)d_out;
    float* outE = outW + (size_t)B_ * T1_ * D_;

    hipError_t e = hipFuncSetAttribute((const void*)enc_split,
                                       hipFuncAttributeMaxDynamicSharedMemorySize,
                                       LDS_TOT);
    if (e == hipSuccess) {
        enc_split<<<dim3(B_ / MB_), dim3(1024), LDS_TOT, stream>>>(
            in, Wih, Whh, bih, bhh, aw, outW, outE);
    } else {
        enc_fused<<<dim3(B_ / MB_), dim3(512), 0, stream>>>(
            in, Wih, Whh, bih, bhh, aw, outW, outE);
    }
}

// Round 26
// 46.094 us; speedup vs baseline: 1.4306x; 1.2587x over previous
//
#include <hip/hip_runtime.h>

#define B_   2048
#define T1_  31
#define D_   128
#define MB_  8
#define XWSZ 61440

typedef __attribute__((ext_vector_type(8))) short bf16x8;
typedef __attribute__((ext_vector_type(4))) float f32x4;
typedef __attribute__((ext_vector_type(2))) float f32x2;

#define L2E  1.4426950408889634f
#define L2E2 2.8853900817779268f

__device__ __forceinline__ unsigned cvt_pk_bf16(float lo, float hi) {
    unsigned r;
    asm("v_cvt_pk_bf16_f32 %0, %1, %2" : "=v"(r) : "v"(lo), "v"(hi));
    return r;
}
__device__ __forceinline__ float rcpf_(float x)  { return __builtin_amdgcn_rcpf(x); }
__device__ __forceinline__ float exp2f_(float x) { return __builtin_amdgcn_exp2f(x); }
// inputs pre-scaled by log2e: sig(x) = rcp(1 + 2^-x'); neg folds into v_exp modifier
__device__ __forceinline__ float sg(float xp)  { return rcpf_(1.0f + exp2f_(-xp)); }
// y = 2*log2e*x: tanh(x) = 1 - 2*rcp(1 + 2^y); saturates correctly at +-inf
__device__ __forceinline__ float th2(float y)  { return fmaf(-2.0f, rcpf_(1.0f + exp2f_(y)), 1.0f); }

#define BAR_LDS() asm volatile("s_waitcnt lgkmcnt(0)\n\ts_barrier" ::: "memory")

// FINAL (R23 structure, best measured: 46.2 us, 2.25x over round-1 baseline).
// 256 blocks x 512 threads; block owns 8 batches for all 31 steps.
// - attention softmax is time-invariant (score = per-batch scalar + x_score;
//   softmax shift-invariant) -> computed once; w_h, w_c, attn_b are dead.
// - wx staged once (bf16, XOR-swizzled LDS); h recurrence via 4 KB LDS dbuf.
// - per-step window: [bar] -> hfr ds_read -> h-MFMA 4-chain seeded with carried
//   accx(t) -> depth-2 wx prefetch -> accx(t+1) from resident frags (latency
//   hides under EW) -> exp2-based EW (weights prescaled by log2e) -> h write ->
//   NT global stores (stay in flight) -> [bar, LDS-only: no vmcnt drain].
// - full 31-step unroll: all LDS ops are fixed-vaddr + constant-offset.
// Ceiling: mathematically serial LSTM recurrence (dependency-bound; all pipes
// <25% busy). Structural escapes tested and falsified: global-ws staging (R14),
// barrier-free self-paced (R15 probe), 16-wave role-split (R24/R25).
__global__ __launch_bounds__(512, 2) void enc_fused(
    const float* __restrict__ in,    // [B][31][128]
    const float* __restrict__ Wih,   // [512][128]
    const float* __restrict__ Whh,   // [512][128]
    const float* __restrict__ bih,   // [512]
    const float* __restrict__ bhh,   // [512]
    const float* __restrict__ aw,    // [287]
    float* __restrict__ outW,        // [B][31][128]
    float* __restrict__ outE)        // [B][31][128]
{
    const int tid  = threadIdx.x;
    const int lane = tid & 63;
    const int wv   = tid >> 6;        // wave 0..7
    const int b0   = blockIdx.x * MB_;
    const int l15  = lane & 15;
    const int lq   = lane >> 4;

    __shared__ __align__(16) char L[XWSZ + 4096];   // [0,61440): wx slots; above: h dbuf

    // ---------------- issue x loads first (HBM, longest latency) ---------------
    const int mg = wv;
    const int d0 = 2 * lane;
    const float* pin = in + (size_t)(b0 + mg) * (T1_ * D_) + d0;
    float2 xc[T1_];
    #pragma unroll
    for (int t = 0; t < T1_; ++t)
        xc[t] = *(const float2*)(pin + t * D_);

    // ---------------- weight fragments -> registers (prescaled, L3-hot) --------
    bf16x8 bw[4][8];
    #pragma unroll
    for (int s = 0; s < 4; ++s) {
        const float scl = (s == 2) ? L2E2 : L2E;    // g-gate section gets 2*log2e
        int n = s * 128 + wv * 16 + l15;
        #pragma unroll
        for (int kf = 0; kf < 8; ++kf) {
            int kb = kf * 32 + lq * 8;
            const float* wp = (kf < 4) ? (Wih + n * D_ + kb) : (Whh + n * D_ + (kb - 128));
            float4 fa = *(const float4*)(wp);
            float4 fb = *(const float4*)(wp + 4);
            union { bf16x8 v; unsigned u[4]; } tmp;
            tmp.u[0] = cvt_pk_bf16(fa.x * scl, fa.y * scl);
            tmp.u[1] = cvt_pk_bf16(fa.z * scl, fa.w * scl);
            tmp.u[2] = cvt_pk_bf16(fb.x * scl, fb.y * scl);
            tmp.u[3] = cvt_pk_bf16(fb.z * scl, fb.w * scl);
            bw[s][kf] = tmp.v;
        }
    }
    const int col = wv * 16 + l15;
    const float bsv[4] = { (bih[col]       + bhh[col])       * L2E,
                           (bih[128 + col] + bhh[128 + col]) * L2E,
                           (bih[256 + col] + bhh[256 + col]) * L2E2,
                           (bih[384 + col] + bhh[384 + col]) * L2E };

    // ---------------- x_score + pure-shfl softmax (exp2) -----------------------
    float xs0 = 0.f, xs1 = 0.f;
    #pragma unroll
    for (int t = 0; t < T1_; ++t) {
        float wt = aw[2 * D_ + t];
        xs0 = fmaf(wt, xc[t].x, xs0);
        xs1 = fmaf(wt, xc[t].y, xs1);
    }
    float mx = fmaxf(xs0, xs1);
    #pragma unroll
    for (int o = 32; o > 0; o >>= 1) mx = fmaxf(mx, __shfl_xor(mx, o));
    float e0 = exp2f_((xs0 - mx) * L2E), e1 = exp2f_((xs1 - mx) * L2E);
    float ss = e0 + e1;
    #pragma unroll
    for (int o = 32; o > 0; o >>= 1) ss += __shfl_xor(ss, o);
    float inv = 1.0f / ss;
    const float a0 = e0 * inv;
    const float a1 = e1 * inv;

    // ---------------- wx staging: outW (NT) + L (swizzled bf16) ----------------
    const int wxbyte = (4 * lane) ^ (mg << 4);
    float* outWp = outW + (size_t)(b0 + mg) * (T1_ * D_) + d0;
    unsigned wx30 = 0;
    #pragma unroll
    for (int t = 0; t < T1_; ++t) {
        float w0 = a0 * xc[t].x, w1 = a1 * xc[t].y;
        f32x2 wsv; wsv[0] = w0; wsv[1] = w1;
        __builtin_nontemporal_store(wsv, (f32x2*)(outWp + t * D_));
        unsigned u = cvt_pk_bf16(w0, w1);
        if (t < 30) *(unsigned*)(L + t * 2048 + mg * 256 + wxbyte) = u;
        else        wx30 = u;
    }
    ((unsigned*)(L + XWSZ))[tid]       = 0u;   // h(0) = 0, both buffers
    ((unsigned*)(L + XWSZ))[tid + 512] = 0u;
    BAR_LDS();

    // ---------------- fixed per-lane LDS vaddrs --------------------------------
    const int arow = l15 & 7;          // A-frag row (rows 8-15 replicate 0-7)
    const int asw  = arow << 4;
    const char* vb[4];
    #pragma unroll
    for (int kf = 0; kf < 4; ++kf)
        vb[kf] = L + arow * 256 + ((kf * 64 + lq * 16) ^ asw);
    // wx slot s:   vb[kf] + s*2048              (imm <= 59392)
    // hfr (t):     vb[kf] + XWSZ + (t&1)*2048   (imm <= 63488)

    const int rb   = ((lane & 31) >> 4) * 4 + ((lane >> 5) << 1);
    const bool hi32 = (lane >= 32);
    const int wb0 = rb * 256       + ((2 * col) ^ (rb << 4));
    const int wb1 = (rb + 1) * 256 + ((2 * col) ^ ((rb + 1) << 4));
    float* outE0 = outE + (size_t)(b0 + rb)     * (T1_ * D_) + col;
    float* outE1 = outE + (size_t)(b0 + rb + 1) * (T1_ * D_) + col;

    float cs0 = 0.f, cs1 = 0.f;
    f32x4 accx[4];
    bf16x8 wxn[4];
    {   // prologue: accx for t=0; wxn = frags(t=1)
        bf16x8 w0[4];
        #pragma unroll
        for (int kf = 0; kf < 4; ++kf)
            w0[kf] = *(const bf16x8*)(vb[kf]);
        #pragma unroll
        for (int s = 0; s < 4; ++s) {
            float b = bsv[s];
            f32x4 aA = {b, b, b, b};
            #pragma unroll
            for (int kf = 0; kf < 4; ++kf)
                aA = __builtin_amdgcn_mfma_f32_16x16x32_bf16(w0[kf], bw[s][kf], aA, 0, 0, 0);
            accx[s] = aA;
        }
        #pragma unroll
        for (int kf = 0; kf < 4; ++kf)
            wxn[kf] = *(const bf16x8*)(vb[kf] + 2048);
    }

    #pragma unroll
    for (int t = 0; t < T1_; ++t) {
        // h fragments for this step (constant offset under unroll)
        bf16x8 hfr[4];
        #pragma unroll
        for (int kf = 0; kf < 4; ++kf)
            hfr[kf] = *(const bf16x8*)(vb[kf] + XWSZ + (t & 1) * 2048);

        // gates = accx(t) [carried] + h @ Whh^T (4-deep seeded chain)
        f32x4 acc[4];
        #pragma unroll
        for (int s = 0; s < 4; ++s) {
            f32x4 a_ = accx[s];
            #pragma unroll
            for (int kf = 0; kf < 4; ++kf)
                a_ = __builtin_amdgcn_mfma_f32_16x16x32_bf16(hfr[kf], bw[s][4 + kf], a_, 0, 0, 0);
            acc[s] = a_;
        }

        // depth-2 prefetch: frags(t+2); constant slot under unroll
        bf16x8 wxn2[4];
        if (t < 29) {
            const int slot = (t + 2 == 30) ? 0 : (t + 2);
            #pragma unroll
            for (int kf = 0; kf < 4; ++kf)
                wxn2[kf] = *(const bf16x8*)(vb[kf] + slot * 2048);
        }
        if (t == 1)   // recycle slot 0 with wx[30]; t=0 reads done at barrier(0)
            *(unsigned*)(L + mg * 256 + wxbyte) = wx30;

        // accx(t+1) from resident wxn: MFMA latency hides under EW below
        if (t < 30) {
            #pragma unroll
            for (int s = 0; s < 4; ++s) {
                float b = bsv[s];
                f32x4 aA = {b, b, b, b};
                #pragma unroll
                for (int kf = 0; kf < 4; ++kf)
                    aA = __builtin_amdgcn_mfma_f32_16x16x32_bf16(wxn[kf], bw[s][kf], aA, 0, 0, 0);
                accx[s] = aA;
            }
        }

        // row select via replication
        float gq0[4], gq1[4];
        #pragma unroll
        for (int s = 0; s < 4; ++s) {
            gq0[s] = hi32 ? acc[s][2] : acc[s][0];
            gq1[s] = hi32 ? acc[s][3] : acc[s][1];
        }

        // elementwise (prescaled): 2 independent cells
        float si0 = sg(gq0[0]), si1 = sg(gq1[0]);
        float sf0 = sg(gq0[1]), sf1 = sg(gq1[1]);
        float tg0 = th2(gq0[2]), tg1 = th2(gq1[2]);   // g pre-scaled by 2*log2e
        float so0 = sg(gq0[3]), so1 = sg(gq1[3]);
        float cn0 = fmaf(sf0, cs0, si0 * tg0);  cs0 = cn0;
        float cn1 = fmaf(sf1, cs1, si1 * tg1);  cs1 = cn1;
        float hh0 = so0 * th2(cn0 * L2E2);
        float hh1 = so1 * th2(cn1 * L2E2);
        unsigned hu = cvt_pk_bf16(hh0, hh1);

        // h LDS write (gates barrier); global NT stores after (don't gate)
        if (t < 30) {
            char* hw = L + XWSZ + (((t + 1) & 1) * 2048);
            *(unsigned short*)(hw + wb0) = (unsigned short)(hu & 0xffffu);
            *(unsigned short*)(hw + wb1) = (unsigned short)(hu >> 16);
        }
        __builtin_nontemporal_store(hh0, outE0 + t * D_);
        __builtin_nontemporal_store(hh1, outE1 + t * D_);

        if (t < 29) {
            #pragma unroll
            for (int kf = 0; kf < 4; ++kf) wxn[kf] = wxn2[kf];   // SSA rename under unroll
        }

        BAR_LDS();   // LDS-only visibility; global ops stay in flight
    }
}

extern "C" void kernel_launch(void* const* d_in, const int* in_sizes, int n_in,
                              void* d_out, int out_size, void* d_ws, size_t ws_size,
                              hipStream_t stream) {
    const float* in  = (const float*)d_in[0];
    const float* Wih = (const float*)d_in[1];
    const float* Whh = (const float*)d_in[2];
    const float* bih = (const float*)d_in[3];
    const float* bhh = (const float*)d_in[4];
    const float* aw  = (const float*)d_in[5];
    // d_in[6] (attn_b) is mathematically dead: softmax is shift-invariant.

    float* outW = (float*)d_out;
    float* outE = outW + (size_t)B_ * T1_ * D_;

    enc_fused<<<dim3(B_ / MB_), dim3(512), 0, stream>>>(in, Wih, Whh, bih, bhh, aw, outW, outE);
}